// Round 16
// baseline (1276.960 us; speedup 1.0000x reference)
//
#include <hip/hip_runtime.h>

// S2VT + attention — R16: R13 base (best, 1184us) + fused f32->bf16 GEMM staging
//  (all k_cvt passes deleted; AF32/BF16 template flags, same f2bf rounding) +
//  32KB LDS cache of wpd h-half first 2 ks-groups in dec (wat_c pattern).
//  R15's ENC2 reverted (L2 spill: FETCH 60->346MB).

#define DEV __device__ __forceinline__

typedef __attribute__((ext_vector_type(4))) float f32x4;
typedef __attribute__((ext_vector_type(8))) short bf16x8;
typedef _Float16 half2_t __attribute__((ext_vector_type(2)));

static constexpr int B_ = 64, T_ = 80, H_ = 512, L_ = 31, NDEC = 30;

DEV unsigned short f2bf(float f) {
  unsigned u = __builtin_bit_cast(unsigned, f);
  u += 0x7FFF + ((u >> 16) & 1);
  return (unsigned short)(u >> 16);
}
DEV float bf2f(unsigned short s) {
  unsigned u = (unsigned)s << 16;
  return __builtin_bit_cast(float, u);
}
DEV unsigned short f2h(float x) { return __builtin_bit_cast(unsigned short, (_Float16)x); }
DEV float h2f(unsigned short h) { return (float)__builtin_bit_cast(_Float16, h); }
DEV unsigned f2h2(float lo, float hi) { return (unsigned)f2h(lo) | ((unsigned)f2h(hi) << 16); }
DEV float fdot2(unsigned x, unsigned w, float acc) {
  return __builtin_amdgcn_fdot2(__builtin_bit_cast(half2_t, x),
                                __builtin_bit_cast(half2_t, w), acc, false);
}
DEV float4 acc8(float4 a, uint4 hv, uint4 w0, uint4 w1, uint4 w2, uint4 w3) {
  a.x = fdot2(hv.x, w0.x, a.x); a.y = fdot2(hv.x, w0.y, a.y);
  a.z = fdot2(hv.x, w0.z, a.z); a.w = fdot2(hv.x, w0.w, a.w);
  a.x = fdot2(hv.y, w1.x, a.x); a.y = fdot2(hv.y, w1.y, a.y);
  a.z = fdot2(hv.y, w1.z, a.z); a.w = fdot2(hv.y, w1.w, a.w);
  a.x = fdot2(hv.z, w2.x, a.x); a.y = fdot2(hv.z, w2.y, a.y);
  a.z = fdot2(hv.z, w2.z, a.z); a.w = fdot2(hv.z, w2.w, a.w);
  a.x = fdot2(hv.w, w3.x, a.x); a.y = fdot2(hv.w, w3.y, a.y);
  a.z = fdot2(hv.w, w3.z, a.z); a.w = fdot2(hv.w, w3.w, a.w);
  return a;
}
DEV float accS(float s, uint4 hv, uint4 w) {
  s = fdot2(hv.x, w.x, s); s = fdot2(hv.y, w.y, s);
  s = fdot2(hv.z, w.z, s); s = fdot2(hv.w, w.w, s);
  return s;
}
DEV float sigmoidf(float x) { return 1.f / (1.f + __expf(-x)); }
DEV float tanh_fast(float x) { float e = __expf(2.f * x); return (e - 1.f) / (e + 1.f); }

DEV void astf(float* p, float v) { __hip_atomic_store(p, v, __ATOMIC_RELAXED, __HIP_MEMORY_SCOPE_AGENT); }
DEV void astu(unsigned* p, unsigned v) { __hip_atomic_store(p, v, __ATOMIC_RELAXED, __HIP_MEMORY_SCOPE_AGENT); }
DEV void asti(int* p, int v) { __hip_atomic_store(p, v, __ATOMIC_RELAXED, __HIP_MEMORY_SCOPE_AGENT); }
DEV float aldf(const float* p) { return __hip_atomic_load((float*)p, __ATOMIC_RELAXED, __HIP_MEMORY_SCOPE_AGENT); }
DEV unsigned aldu(const unsigned* p) { return __hip_atomic_load((unsigned*)p, __ATOMIC_RELAXED, __HIP_MEMORY_SCOPE_AGENT); }
DEV int aldi(const int* p) { return __hip_atomic_load((int*)p, __ATOMIC_RELAXED, __HIP_MEMORY_SCOPE_AGENT); }

// 8-member team sync: member m stores its padded flag line; all poll 8 lines.
DEV void tsync8(int* tf, int m, int ph) {
  __syncthreads();
  if (threadIdx.x == 0) asti(tf + m * 16, ph);
  if (threadIdx.x < 8)
    while (aldi(tf + (int)threadIdx.x * 16) < ph) __builtin_amdgcn_s_sleep(1);
  __syncthreads();
}

// load 8 f32 -> 8 bf16 packed in a uint4 (same rounding as old k_cvt)
DEV uint4 ldcvt(const float* p) {
  float4 v0 = *(const float4*)p;
  float4 v1 = *(const float4*)(p + 4);
  uint4 r;
  r.x = (unsigned)f2bf(v0.x) | ((unsigned)f2bf(v0.y) << 16);
  r.y = (unsigned)f2bf(v0.z) | ((unsigned)f2bf(v0.w) << 16);
  r.z = (unsigned)f2bf(v1.x) | ((unsigned)f2bf(v1.y) << 16);
  r.w = (unsigned)f2bf(v1.z) | ((unsigned)f2bf(v1.w) << 16);
  return r;
}

// ---------------- int64-vs-int32 caption detect ----------------
__global__ void k_detect_i64(const int* __restrict__ cap, int* __restrict__ flag) {
  __shared__ int s;
  if (threadIdx.x == 0) s = 0;
  __syncthreads();
  int acc = 0;
  for (int i = threadIdx.x; i < (B_ * L_) / 2; i += 256) acc |= cap[2 * i + 1];
  if (acc) atomicOr(&s, 1);
  __syncthreads();
  if (threadIdx.x == 0) flag[0] = (s == 0) ? 1 : 0;
}

// ---------------- embedding gather (rows r = l*64+b) ----------------
__global__ __launch_bounds__(256) void k_gather_emb(const float* __restrict__ emb,
                                                    const int* __restrict__ cap,
                                                    const int* __restrict__ flag,
                                                    unsigned short* __restrict__ aemb) {
  int r = blockIdx.x;
  int l = r >> 6, b = r & 63;
  int ci = b * L_ + l;
  int tok = flag[0] ? cap[2 * ci] : cap[ci];
  const float* src = emb + (size_t)tok * H_;
  unsigned short* dst = aemb + (size_t)r * H_;
  for (int c = threadIdx.x; c < H_; c += 256) dst[c] = f2bf(src[c]);
}

// ---------------- f16 weight pack kernels (one-time) ----------------
__global__ __launch_bounds__(256) void k_pack_enc(const float* __restrict__ whh,
                                                  uint4* __restrict__ wpe) {
  int idx = blockIdx.x * 256 + threadIdx.x;  // k2(256) x j(512)
  int k2 = idx >> 9, j = idx & 511;
  float2 r0 = *(const float2*)(whh + (size_t)(j) * 512 + 2 * k2);
  float2 r1 = *(const float2*)(whh + (size_t)(512 + j) * 512 + 2 * k2);
  float2 r2 = *(const float2*)(whh + (size_t)(1024 + j) * 512 + 2 * k2);
  float2 r3 = *(const float2*)(whh + (size_t)(1536 + j) * 512 + 2 * k2);
  wpe[idx] = make_uint4(f2h2(r0.x, r0.y), f2h2(r1.x, r1.y), f2h2(r2.x, r2.y), f2h2(r3.x, r3.y));
}

__global__ __launch_bounds__(256) void k_pack_dec(const float* __restrict__ dwih,
                                                  const float* __restrict__ dwhh,
                                                  uint4* __restrict__ wpd) {
  int idx = blockIdx.x * 256 + threadIdx.x;  // k2(512) x j(512)
  int k2 = idx >> 9, j = idx & 511;
  float2 r[4];
  if (k2 < 256) {
#pragma unroll
    for (int g = 0; g < 4; ++g)
      r[g] = *(const float2*)(dwih + (size_t)(g * 512 + j) * 1024 + 512 + 2 * k2);
  } else {
#pragma unroll
    for (int g = 0; g < 4; ++g)
      r[g] = *(const float2*)(dwhh + (size_t)(g * 512 + j) * 512 + 2 * (k2 - 256));
  }
  wpd[idx] = make_uint4(f2h2(r[0].x, r[0].y), f2h2(r[1].x, r[1].y),
                        f2h2(r[2].x, r[2].y), f2h2(r[3].x, r[3].y));
}

__global__ __launch_bounds__(256) void k_pack_attn2(const float* __restrict__ attnw,
                                                    uint4* __restrict__ wat2) {
  int idx = blockIdx.x * 256 + threadIdx.x;  // k8(64) x u(512)
  int k8 = idx >> 9, u = idx & 511;
  const float* p = attnw + (size_t)u * 1024 + 8 * k8;
  wat2[idx] = make_uint4(f2h2(p[0], p[1]), f2h2(p[2], p[3]),
                         f2h2(p[4], p[5]), f2h2(p[6], p[7]));
}

// ---------------- bf16 MFMA GEMM, reg-prefetch, optional fused f32->bf16 ----------------
// OUT_MODE 0: row-major; 1: FC row remap; 2: gate-packed f32 [row][j][4]
// AF32/BF32: operand stored as f32; staging converts with f2bf.
template <int OUT_MODE, int AF32, int BF32>
__global__ __launch_bounds__(256) void k_gemm(const void* __restrict__ Av, int lda,
                                              const void* __restrict__ Bv, int ldb,
                                              float* __restrict__ C, int N, int K,
                                              const float* __restrict__ bias0,
                                              const float* __restrict__ bias1) {
  __shared__ __align__(16) unsigned short As[128 * 40];
  __shared__ __align__(16) unsigned short Bs[128 * 40];
  const int tid = threadIdx.x;
  const int m0 = blockIdx.y * 128, n0 = blockIdx.x * 128;
  const int wave = tid >> 6, lane = tid & 63;
  const int wm = wave >> 1, wn = wave & 1;
  const int lr = lane & 15, lk = lane >> 4;

  const unsigned short* A16 = (const unsigned short*)Av;
  const float* A32 = (const float*)Av;
  const unsigned short* B16 = (const unsigned short*)Bv;
  const float* B32 = (const float*)Bv;

  f32x4 acc[4][4];
#pragma unroll
  for (int m = 0; m < 4; ++m)
#pragma unroll
    for (int n = 0; n < 4; ++n) acc[m][n] = (f32x4){0.f, 0.f, 0.f, 0.f};

  const int c0 = tid, c1 = tid + 256;
  const int ar0 = c0 >> 2, as0 = c0 & 3;
  const int ar1 = c1 >> 2, as1 = c1 & 3;

  auto loadA = [&](int row, int k) -> uint4 {
    if (AF32) return ldcvt(A32 + (size_t)row * lda + k);
    return *(const uint4*)(A16 + (size_t)row * lda + k);
  };
  auto loadB = [&](int row, int k) -> uint4 {
    if (BF32) return ldcvt(B32 + (size_t)row * ldb + k);
    return *(const uint4*)(B16 + (size_t)row * ldb + k);
  };

  uint4 va0 = loadA(m0 + ar0, as0 * 8);
  uint4 va1 = loadA(m0 + ar1, as1 * 8);
  uint4 vb0 = loadB(n0 + ar0, as0 * 8);
  uint4 vb1 = loadB(n0 + ar1, as1 * 8);

  for (int k0 = 0; k0 < K; k0 += 32) {
    *(uint4*)(As + ar0 * 40 + as0 * 8) = va0;
    *(uint4*)(As + ar1 * 40 + as1 * 8) = va1;
    *(uint4*)(Bs + ar0 * 40 + as0 * 8) = vb0;
    *(uint4*)(Bs + ar1 * 40 + as1 * 8) = vb1;
    __syncthreads();
    if (k0 + 32 < K) {
      va0 = loadA(m0 + ar0, k0 + 32 + as0 * 8);
      va1 = loadA(m0 + ar1, k0 + 32 + as1 * 8);
      vb0 = loadB(n0 + ar0, k0 + 32 + as0 * 8);
      vb1 = loadB(n0 + ar1, k0 + 32 + as1 * 8);
    }
    bf16x8 af[4], bfr[4];
#pragma unroll
    for (int m = 0; m < 4; ++m)
      af[m] = *(const bf16x8*)(As + (wm * 64 + m * 16 + lr) * 40 + lk * 8);
#pragma unroll
    for (int n = 0; n < 4; ++n)
      bfr[n] = *(const bf16x8*)(Bs + (wn * 64 + n * 16 + lr) * 40 + lk * 8);
#pragma unroll
    for (int m = 0; m < 4; ++m)
#pragma unroll
      for (int n = 0; n < 4; ++n)
        acc[m][n] = __builtin_amdgcn_mfma_f32_16x16x32_bf16(af[m], bfr[n], acc[m][n], 0, 0, 0);
    __syncthreads();
  }
#pragma unroll
  for (int m = 0; m < 4; ++m) {
#pragma unroll
    for (int n = 0; n < 4; ++n) {
      const int col = n0 + wn * 64 + n * 16 + lr;
      float bv = (bias0 ? bias0[col] : 0.f) + (bias1 ? bias1[col] : 0.f);
#pragma unroll
      for (int j = 0; j < 4; ++j) {
        const int row = m0 + wm * 64 + m * 16 + lk * 4 + j;
        float v = acc[m][n][j] + bv;
        if (OUT_MODE == 0) {
          C[(size_t)row * N + col] = v;
        } else if (OUT_MODE == 1) {
          int l = row >> 6, b = row & 63;
          C[((size_t)b * NDEC + l) * (size_t)N + col] = v;
        } else {
          C[((size_t)row * 512 + (col & 511)) * 4 + (col >> 9)] = v;
        }
      }
    }
  }
}

// ---------------- encoder: 8-block team, 2 b's (R13 verbatim) ----------------
__global__ __launch_bounds__(1024) void k_enc6(const float4* __restrict__ xg4,
                                               const uint4* __restrict__ wpe,
                                               float* __restrict__ encf,
                                               unsigned short* __restrict__ encbf,
                                               float* __restrict__ cfin,
                                               unsigned* __restrict__ h16E,  // [2][64][256]
                                               int* __restrict__ flagsE) {
  __shared__ __align__(16) unsigned short h16[2][512];
  __shared__ __align__(16) float psumG[2][16][4][64];  // 32 KB
  __shared__ __align__(16) float gsum[2][4][64];
  __shared__ unsigned short hnew[2][64];
  __shared__ __align__(16) uint4 wcache[112 * 64];     // 112 KB: k2<112, own j-slice
  const int bid = blockIdx.x, team = bid >> 3, m = bid & 7, tid = threadIdx.x;
  const int J0 = m * 64;
  int* tf = flagsE + team * 128;
  for (int i = tid; i < 112 * 64; i += 1024)
    wcache[i] = wpe[((i >> 6) << 9) | (J0 + (i & 63))];
  if (tid < 512) { h16[0][tid] = 0; h16[1][tid] = 0; }
  float c = 0.f;
  __syncthreads();
  const int j64 = tid & 63, ks = tid >> 6;   // 16 k-splits
  const int j = J0 + j64;
  const uint4* hp0 = (const uint4*)h16[0];
  const uint4* hp1 = (const uint4*)h16[1];
  for (int t = 0; t < T_; ++t) {
    float4 a0 = {0.f, 0.f, 0.f, 0.f}, a1 = a0;
    if (ks < 7) {
#pragma unroll
      for (int ii = 0; ii < 4; ++ii) {
        const int k8 = ks * 4 + ii;
        uint4 h0 = hp0[k8], h1 = hp1[k8];
        uint4 w0 = wcache[((k8 * 4 + 0) << 6) | j64];
        uint4 w1 = wcache[((k8 * 4 + 1) << 6) | j64];
        uint4 w2 = wcache[((k8 * 4 + 2) << 6) | j64];
        uint4 w3 = wcache[((k8 * 4 + 3) << 6) | j64];
        a0 = acc8(a0, h0, w0, w1, w2, w3);
        a1 = acc8(a1, h1, w0, w1, w2, w3);
      }
    } else {
#pragma unroll 2
      for (int ii = 0; ii < 4; ++ii) {
        const int k8 = ks * 4 + ii;
        uint4 h0 = hp0[k8], h1 = hp1[k8];
        uint4 w0 = wpe[((k8 * 4 + 0) << 9) | j];
        uint4 w1 = wpe[((k8 * 4 + 1) << 9) | j];
        uint4 w2 = wpe[((k8 * 4 + 2) << 9) | j];
        uint4 w3 = wpe[((k8 * 4 + 3) << 9) | j];
        a0 = acc8(a0, h0, w0, w1, w2, w3);
        a1 = acc8(a1, h1, w0, w1, w2, w3);
      }
    }
    psumG[0][ks][0][j64] = a0.x; psumG[0][ks][1][j64] = a0.y;
    psumG[0][ks][2][j64] = a0.z; psumG[0][ks][3][j64] = a0.w;
    psumG[1][ks][0][j64] = a1.x; psumG[1][ks][1][j64] = a1.y;
    psumG[1][ks][2][j64] = a1.z; psumG[1][ks][3][j64] = a1.w;
    __syncthreads();
    if (tid < 512) {
      const int b2 = tid >> 8, g = (tid >> 6) & 3, jj = tid & 63;
      float s = 0.f;
#pragma unroll
      for (int q = 0; q < 16; ++q) s += psumG[b2][q][g][jj];
      gsum[b2][g][jj] = s;
    }
    __syncthreads();
    if (tid < 128) {
      const int b2 = tid >> 6, jj = tid & 63;
      const int b = team * 2 + b2;
      float4 xa = xg4[((size_t)b * T_ + t) * 512 + J0 + jj];
      float g0 = xa.x + gsum[b2][0][jj];
      float g1 = xa.y + gsum[b2][1][jj];
      float g2 = xa.z + gsum[b2][2][jj];
      float g3 = xa.w + gsum[b2][3][jj];
      c = sigmoidf(g1) * c + sigmoidf(g0) * tanh_fast(g2);
      float h = sigmoidf(g3) * tanh_fast(c);
      size_t o = ((size_t)b * T_ + t) * 512 + J0 + jj;
      encf[o] = h;
      encbf[o] = f2bf(h);
      hnew[b2][jj] = f2h(h);
      if (t == T_ - 1) cfin[(size_t)b * 512 + J0 + jj] = c;
    }
    __syncthreads();
    const int p = t & 1;
    if (tid < 64) {
      const int b2 = tid >> 5, pp = tid & 31;
      const int b = team * 2 + b2;
      astu(h16E + (size_t)p * 64 * 256 + b * 256 + (J0 >> 1) + pp,
           f2h2(h2f(hnew[b2][2 * pp]), h2f(hnew[b2][2 * pp + 1])));
    }
    tsync8(tf, m, t + 1);
    if (t < T_ - 1) {
      if (tid < 512) {
        const int b2 = tid >> 8, pp = tid & 255;
        const int b = team * 2 + b2;
        ((unsigned*)h16[b2])[pp] = aldu(h16E + (size_t)p * 64 * 256 + b * 256 + pp);
      }
      __syncthreads();
    }
  }
}

// ---------------- decoder: 8-block team, 2 b's; 3 syncs/step; wat2 + partial wpd LDS-cached ----------------
__global__ __launch_bounds__(1024) void k_dec8(const uint4* __restrict__ wpd,
                                               const uint4* __restrict__ wat2,
                                               const float* __restrict__ vw,
                                               const float4* __restrict__ eg4,
                                               const float* __restrict__ encpart,
                                               const unsigned short* __restrict__ encbf,
                                               const float* __restrict__ encf,
                                               const float* __restrict__ cfin,
                                               unsigned short* __restrict__ hsbf,
                                               float* __restrict__ scpart,   // [64][8][80]
                                               unsigned* __restrict__ ctxsl, // [64][256]
                                               unsigned* __restrict__ h16D,  // [2][64][256]
                                               int* __restrict__ flagsD) {
  __shared__ __align__(16) uint4 wat_c[64 * 64];          // 64 KB: wat2 j-slice
  __shared__ __align__(16) uint4 wpdc[32 * 64];           // 32 KB: wpd h-half rows 256..287
  __shared__ __align__(16) unsigned short xv16[2][1024];  // [b][ctx;h] f16
  __shared__ float vsmO[64];
  __shared__ float hwOwn[2][64];
  __shared__ float sc2[2][80], wts2[2][80];
  __shared__ __align__(16) float psumW[2][16][64];        // 8 KB
  __shared__ __align__(16) float psumG[2][16][4][64];     // 32 KB
  __shared__ __align__(16) float gsum[2][4][64];
  __shared__ __align__(16) float ctxp[2][8][64];
  __shared__ unsigned short hnew[2][64];
  const int bid = blockIdx.x, team = bid >> 3, m = bid & 7, tid = threadIdx.x;
  const int J0 = m * 64;
  int* tf = flagsD + team * 128;
  for (int i = tid; i < 64 * 64; i += 1024)
    wat_c[i] = wat2[((i >> 6) << 9) | (J0 + (i & 63))];
  for (int i = tid; i < 32 * 64; i += 1024)
    wpdc[i] = wpd[((256 + (i >> 6)) << 9) | (J0 + (i & 63))];
  {
    const int b2 = tid >> 9, jj = tid & 511;
    xv16[b2][512 + jj] = f2h(encf[((size_t)(team * 2 + b2) * T_ + T_ - 1) * 512 + jj]);
  }
  if (tid < 64) vsmO[tid] = vw[J0 + tid];
  float c = 0.f;
  if (tid < 128) c = cfin[(size_t)(team * 2 + (tid >> 6)) * 512 + J0 + (tid & 63)];
  __syncthreads();
  const int j64 = tid & 63, ks = tid >> 6;   // 16 k-splits
  const int j = J0 + j64;
  const uint4* xp0 = (const uint4*)xv16[0];
  const uint4* xp1 = (const uint4*)xv16[1];

  for (int l = 0; l < NDEC; ++l) {
    // ---- Phase A: gates h-half + hW, both b's, weight loaded once ----
    {
      float4 a0 = {0.f, 0.f, 0.f, 0.f}, a1 = a0;
      float s0 = 0.f, s1 = 0.f;
      if (ks < 2) {
#pragma unroll 2
        for (int ii = 0; ii < 4; ++ii) {
          const int ka = ks * 4 + ii;      // h-dim k8 in [0,8)
          const int kg = 64 + ka;
          uint4 hx0 = xp0[kg], hx1 = xp1[kg];
          uint4 w0 = wpdc[((ka * 4 + 0) << 6) | j64];
          uint4 w1 = wpdc[((ka * 4 + 1) << 6) | j64];
          uint4 w2 = wpdc[((ka * 4 + 2) << 6) | j64];
          uint4 w3 = wpdc[((ka * 4 + 3) << 6) | j64];
          a0 = acc8(a0, hx0, w0, w1, w2, w3);
          a1 = acc8(a1, hx1, w0, w1, w2, w3);
          uint4 wa = wat_c[(ka << 6) | j64];
          s0 = accS(s0, hx0, wa);
          s1 = accS(s1, hx1, wa);
        }
      } else {
#pragma unroll 2
        for (int ii = 0; ii < 4; ++ii) {
          const int ka = ks * 4 + ii;      // h-dim k8 in [8,64)
          const int kg = 64 + ka;
          uint4 hx0 = xp0[kg], hx1 = xp1[kg];
          uint4 w0 = wpd[((kg * 4 + 0) << 9) | j];
          uint4 w1 = wpd[((kg * 4 + 1) << 9) | j];
          uint4 w2 = wpd[((kg * 4 + 2) << 9) | j];
          uint4 w3 = wpd[((kg * 4 + 3) << 9) | j];
          a0 = acc8(a0, hx0, w0, w1, w2, w3);
          a1 = acc8(a1, hx1, w0, w1, w2, w3);
          uint4 wa = wat_c[(ka << 6) | j64];
          s0 = accS(s0, hx0, wa);
          s1 = accS(s1, hx1, wa);
        }
      }
      psumG[0][ks][0][j64] = a0.x; psumG[0][ks][1][j64] = a0.y;
      psumG[0][ks][2][j64] = a0.z; psumG[0][ks][3][j64] = a0.w;
      psumG[1][ks][0][j64] = a1.x; psumG[1][ks][1][j64] = a1.y;
      psumG[1][ks][2][j64] = a1.z; psumG[1][ks][3][j64] = a1.w;
      psumW[0][ks][j64] = s0;
      psumW[1][ks][j64] = s1;
    }
    __syncthreads();
    if (tid < 128) {
      const int b2 = tid >> 6, jj = tid & 63;
      float s = 0.f;
#pragma unroll
      for (int q = 0; q < 16; ++q) s += psumW[b2][q][jj];
      hwOwn[b2][jj] = s;
    }
    __syncthreads();
    // score partials over own u-slice, all 80 t, both b's
    {
      const int wv = tid >> 6, ln = tid & 63;
      const int b2 = wv & 1, b = team * 2 + b2;
      for (int t = wv >> 1; t < T_; t += 8) {
        float p = vsmO[ln] * tanh_fast(hwOwn[b2][ln] +
                  encpart[((size_t)b * T_ + t) * 512 + J0 + ln]);
#pragma unroll
        for (int s = 1; s < 64; s <<= 1) p += __shfl_xor(p, s, 64);
        if (ln == 0) astf(scpart + ((size_t)b * 8 + m) * 80 + t, p);
      }
    }
    tsync8(tf, m, 3 * l + 1);
    // ---- Phase B: sum partials -> softmax (both b) -> ctx j-slice ----
    if (tid < 160) {
      const int b2 = tid / 80, t = tid % 80;
      const int b = team * 2 + b2;
      float s = 0.f;
#pragma unroll
      for (int mm = 0; mm < 8; ++mm) s += aldf(scpart + ((size_t)b * 8 + mm) * 80 + t);
      sc2[b2][t] = s;
    }
    __syncthreads();
    if (tid < 128) {
      const int b2 = tid >> 6, ln = tid & 63;
      float x0 = sc2[b2][ln];
      float x1 = (ln < 16) ? sc2[b2][64 + ln] : -1e30f;
      float mx = fmaxf(x0, x1);
#pragma unroll
      for (int s = 1; s < 64; s <<= 1) mx = fmaxf(mx, __shfl_xor(mx, s, 64));
      float e0 = __expf(x0 - mx);
      float e1 = (ln < 16) ? __expf(x1 - mx) : 0.f;
      float sm = e0 + e1;
#pragma unroll
      for (int s = 1; s < 64; s <<= 1) sm += __shfl_xor(sm, s, 64);
      wts2[b2][ln] = e0 / sm;
      if (ln < 16) wts2[b2][64 + ln] = e1 / sm;
    }
    __syncthreads();
    // ctx final for own j-slice over all 80 t (10 KB/b read, L2-local)
    {
      const int b2 = tid >> 9, tq = (tid >> 6) & 7, jj = tid & 63;
      const int b = team * 2 + b2;
      float a = 0.f;
      for (int t = tq; t < T_; t += 8)
        a += wts2[b2][t] * bf2f(encbf[((size_t)b * T_ + t) * 512 + J0 + jj]);
      ctxp[b2][tq][jj] = a;
    }
    __syncthreads();
    if (tid < 64) {
      const int b2 = tid >> 5, pp = tid & 31;
      const int b = team * 2 + b2;
      float s0 = 0.f, s1 = 0.f;
#pragma unroll
      for (int q = 0; q < 8; ++q) {
        s0 += ctxp[b2][q][2 * pp];
        s1 += ctxp[b2][q][2 * pp + 1];
      }
      astu(ctxsl + (size_t)b * 256 + (J0 >> 1) + pp, f2h2(s0, s1));
    }
    tsync8(tf, m, 3 * l + 2);
    // ---- Phase C: read full ctx -> gates ctx-half -> LSTM -> h exchange ----
    if (tid < 512) {
      const int b2 = tid >> 8, pp = tid & 255;
      const int b = team * 2 + b2;
      ((unsigned*)xv16[b2])[pp] = aldu(ctxsl + (size_t)b * 256 + pp);
    }
    __syncthreads();
    {
      float4 a0 = {0.f, 0.f, 0.f, 0.f}, a1 = a0;
#pragma unroll 2
      for (int ii = 0; ii < 4; ++ii) {
        const int kc = ks * 4 + ii;        // ctx-dim k8 in [0,64)
        uint4 hx0 = xp0[kc], hx1 = xp1[kc];
        uint4 w0 = wpd[((kc * 4 + 0) << 9) | j];
        uint4 w1 = wpd[((kc * 4 + 1) << 9) | j];
        uint4 w2 = wpd[((kc * 4 + 2) << 9) | j];
        uint4 w3 = wpd[((kc * 4 + 3) << 9) | j];
        a0 = acc8(a0, hx0, w0, w1, w2, w3);
        a1 = acc8(a1, hx1, w0, w1, w2, w3);
      }
      psumG[0][ks][0][j64] += a0.x; psumG[0][ks][1][j64] += a0.y;
      psumG[0][ks][2][j64] += a0.z; psumG[0][ks][3][j64] += a0.w;
      psumG[1][ks][0][j64] += a1.x; psumG[1][ks][1][j64] += a1.y;
      psumG[1][ks][2][j64] += a1.z; psumG[1][ks][3][j64] += a1.w;
    }
    __syncthreads();
    if (tid < 512) {
      const int b2 = tid >> 8, g = (tid >> 6) & 3, jj = tid & 63;
      float s = 0.f;
#pragma unroll
      for (int q = 0; q < 16; ++q) s += psumG[b2][q][g][jj];
      gsum[b2][g][jj] = s;
    }
    __syncthreads();
    if (tid < 128) {
      const int b2 = tid >> 6, jj = tid & 63;
      const int b = team * 2 + b2;
      float4 xa = eg4[((size_t)l * 64 + b) * 512 + J0 + jj];
      float g0 = xa.x + gsum[b2][0][jj];
      float g1 = xa.y + gsum[b2][1][jj];
      float g2 = xa.z + gsum[b2][2][jj];
      float g3 = xa.w + gsum[b2][3][jj];
      c = sigmoidf(g1) * c + sigmoidf(g0) * tanh_fast(g2);
      float h = sigmoidf(g3) * tanh_fast(c);
      hsbf[((size_t)l * 64 + b) * 512 + J0 + jj] = f2bf(h);
      hnew[b2][jj] = f2h(h);
    }
    __syncthreads();
    const int p = l & 1;
    if (tid < 64) {
      const int b2 = tid >> 5, pp = tid & 31;
      const int b = team * 2 + b2;
      astu(h16D + (size_t)p * 64 * 256 + b * 256 + (J0 >> 1) + pp,
           f2h2(h2f(hnew[b2][2 * pp]), h2f(hnew[b2][2 * pp + 1])));
    }
    tsync8(tf, m, 3 * l + 3);
    if (l < NDEC - 1) {
      if (tid < 512) {
        const int b2 = tid >> 8, pp = tid & 255;
        const int b = team * 2 + b2;
        ((unsigned*)(&xv16[b2][512]))[pp] = aldu(h16D + (size_t)p * 64 * 256 + b * 256 + pp);
      }
      __syncthreads();
    }
  }
}

// ---------------- launch ----------------
extern "C" void kernel_launch(void* const* d_in, const int* in_sizes, int n_in,
                              void* d_out, int out_size, void* d_ws, size_t ws_size,
                              hipStream_t stream) {
  const float* video = (const float*)d_in[0];
  const int* captions = (const int*)d_in[1];
  const float* emb = (const float*)d_in[2];
  const float* eWih = (const float*)d_in[3];
  const float* eWhh = (const float*)d_in[4];
  const float* ebih = (const float*)d_in[5];
  const float* ebhh = (const float*)d_in[6];
  const float* attnW = (const float*)d_in[7];
  const float* attnb = (const float*)d_in[8];
  const float* vw = (const float*)d_in[9];
  const float* dWih = (const float*)d_in[10];
  const float* dWhh = (const float*)d_in[11];
  const float* dbih = (const float*)d_in[12];
  const float* dbhh = (const float*)d_in[13];
  const float* fcW = (const float*)d_in[14];
  const float* fcb = (const float*)d_in[15];

  char* ws = (char*)d_ws;
  const size_t G = 32768000ull;  // team-exchange region
  unsigned* h16E = (unsigned*)(ws + G + 0);            // 131,072
  unsigned* h16D = (unsigned*)(ws + G + 131072);       // 131,072
  float* scpartD = (float*)(ws + G + 262144);          // 163,840 ([64][8][80] f32)
  unsigned* ctxslD = (unsigned*)(ws + G + 425984);     // 65,536 ([64][256] u32)
  int* flagsE = (int*)(ws + G + 491520);               // 16,384
  int* flagsD = (int*)(ws + G + 507904);               // 16,384 (ends 524,288)
  unsigned short* hs_bf = (unsigned short*)(ws + 33554432ull);
  uint4* wpd = (uint4*)(ws + 35520512ull);
  uint4* wpe = (uint4*)(ws + 39714816ull);
  float* xg4 = (float*)(ws + 41943040ull);                       // dead after enc
  float* encpart = (float*)(ws + 41943040ull);                   // after enc
  float* eg4 = (float*)(ws + 52428800ull);                       // after enc
  unsigned short* aemb = (unsigned short*)(ws + 68157440ull);
  float* encf = (float*)(ws + 100663296ull);
  unsigned short* encbf = (unsigned short*)(ws + 111149056ull);
  uint4* wat2 = (uint4*)(ws + 121634816ull);
  float* cfin = (float*)(ws + 122159104ull);
  int* flag = (int*)(ws + 122290176ull);

  k_detect_i64<<<1, 256, 0, stream>>>(captions, flag);
  hipMemsetAsync(ws + G + 491520, 0, 32768, stream);

  // K1: X_gates = video(f32) @ eWih(f32)^T + ebih + ebhh -> gate-packed [r][j][4]
  k_gemm<2, 1, 1><<<dim3(16, 40), 256, 0, stream>>>(video, 4096, eWih, 4096, xg4, 2048, 4096, ebih, ebhh);

  // f16 weight packs
  k_pack_enc<<<512, 256, 0, stream>>>(eWhh, wpe);
  k_pack_dec<<<1024, 256, 0, stream>>>(dWih, dWhh, wpd);
  k_pack_attn2<<<128, 256, 0, stream>>>(attnW, wat2);

  k_enc6<<<256, 1024, 0, stream>>>((const float4*)xg4, wpe, encf, encbf, cfin, h16E, flagsE);

  k_gather_emb<<<1920, 256, 0, stream>>>(emb, captions, flag, aemb);
  // EncPart = enc_out(bf16) @ attnW[:,512:](f32)^T + attn_b   [5120 x 512]
  k_gemm<0, 0, 1><<<dim3(4, 40), 256, 0, stream>>>(encbf, 512, attnW + 512, 1024, encpart, 512, 512, attnb, nullptr);
  // E_gates = emb[tok](bf16) @ dWih[:,:512](f32)^T + dbih + dbhh -> gate-packed
  k_gemm<2, 0, 1><<<dim3(16, 15), 256, 0, stream>>>(aemb, 512, dWih, 1024, eg4, 2048, 512, dbih, dbhh);

  k_dec8<<<256, 1024, 0, stream>>>(wpd, wat2, vw, (const float4*)eg4, encpart, encbf, encf,
                                   cfin, hs_bf, scpartD, ctxslD, h16D, flagsD);

  // FC: out[b][l][v] = Hs(bf16) @ fcW(f32)^T + fc_b   [1920 x 32000]
  k_gemm<1, 0, 1><<<dim3(250, 15), 256, 0, stream>>>(hs_bf, 512, fcW, 512, (float*)d_out, 32000, 512, fcb, nullptr);
}

// Round 17
// 1176.280 us; speedup vs baseline: 1.0856x; 1.0856x over previous
//
#include <hip/hip_runtime.h>

// S2VT + attention — R17: best-of composition. R13 verbatim (separate k_cvt +
// bf16 reg-prefetch GEMMs, best total 1184.6us) + R16's single proven win:
// 32KB wpdc LDS cache of wpd h-half rows 256..287 in the decoder (dec 541->536).
// Rejected by measurement: g=4 teams (R12), ENC2 (R15), fused-cvt GEMM (R16),
// global_load_lds GEMM staging (R14).

#define DEV __device__ __forceinline__

typedef __attribute__((ext_vector_type(4))) float f32x4;
typedef __attribute__((ext_vector_type(8))) short bf16x8;
typedef _Float16 half2_t __attribute__((ext_vector_type(2)));

static constexpr int B_ = 64, T_ = 80, H_ = 512, L_ = 31, NDEC = 30;

DEV unsigned short f2bf(float f) {
  unsigned u = __builtin_bit_cast(unsigned, f);
  u += 0x7FFF + ((u >> 16) & 1);
  return (unsigned short)(u >> 16);
}
DEV float bf2f(unsigned short s) {
  unsigned u = (unsigned)s << 16;
  return __builtin_bit_cast(float, u);
}
DEV unsigned short f2h(float x) { return __builtin_bit_cast(unsigned short, (_Float16)x); }
DEV float h2f(unsigned short h) { return (float)__builtin_bit_cast(_Float16, h); }
DEV unsigned f2h2(float lo, float hi) { return (unsigned)f2h(lo) | ((unsigned)f2h(hi) << 16); }
DEV float fdot2(unsigned x, unsigned w, float acc) {
  return __builtin_amdgcn_fdot2(__builtin_bit_cast(half2_t, x),
                                __builtin_bit_cast(half2_t, w), acc, false);
}
DEV float4 acc8(float4 a, uint4 hv, uint4 w0, uint4 w1, uint4 w2, uint4 w3) {
  a.x = fdot2(hv.x, w0.x, a.x); a.y = fdot2(hv.x, w0.y, a.y);
  a.z = fdot2(hv.x, w0.z, a.z); a.w = fdot2(hv.x, w0.w, a.w);
  a.x = fdot2(hv.y, w1.x, a.x); a.y = fdot2(hv.y, w1.y, a.y);
  a.z = fdot2(hv.y, w1.z, a.z); a.w = fdot2(hv.y, w1.w, a.w);
  a.x = fdot2(hv.z, w2.x, a.x); a.y = fdot2(hv.z, w2.y, a.y);
  a.z = fdot2(hv.z, w2.z, a.z); a.w = fdot2(hv.z, w2.w, a.w);
  a.x = fdot2(hv.w, w3.x, a.x); a.y = fdot2(hv.w, w3.y, a.y);
  a.z = fdot2(hv.w, w3.z, a.z); a.w = fdot2(hv.w, w3.w, a.w);
  return a;
}
DEV float accS(float s, uint4 hv, uint4 w) {
  s = fdot2(hv.x, w.x, s); s = fdot2(hv.y, w.y, s);
  s = fdot2(hv.z, w.z, s); s = fdot2(hv.w, w.w, s);
  return s;
}
DEV float sigmoidf(float x) { return 1.f / (1.f + __expf(-x)); }
DEV float tanh_fast(float x) { float e = __expf(2.f * x); return (e - 1.f) / (e + 1.f); }

DEV void astf(float* p, float v) { __hip_atomic_store(p, v, __ATOMIC_RELAXED, __HIP_MEMORY_SCOPE_AGENT); }
DEV void astu(unsigned* p, unsigned v) { __hip_atomic_store(p, v, __ATOMIC_RELAXED, __HIP_MEMORY_SCOPE_AGENT); }
DEV void asti(int* p, int v) { __hip_atomic_store(p, v, __ATOMIC_RELAXED, __HIP_MEMORY_SCOPE_AGENT); }
DEV float aldf(const float* p) { return __hip_atomic_load((float*)p, __ATOMIC_RELAXED, __HIP_MEMORY_SCOPE_AGENT); }
DEV unsigned aldu(const unsigned* p) { return __hip_atomic_load((unsigned*)p, __ATOMIC_RELAXED, __HIP_MEMORY_SCOPE_AGENT); }
DEV int aldi(const int* p) { return __hip_atomic_load((int*)p, __ATOMIC_RELAXED, __HIP_MEMORY_SCOPE_AGENT); }

// 8-member team sync: member m stores its padded flag line; all poll 8 lines.
DEV void tsync8(int* tf, int m, int ph) {
  __syncthreads();
  if (threadIdx.x == 0) asti(tf + m * 16, ph);
  if (threadIdx.x < 8)
    while (aldi(tf + (int)threadIdx.x * 16) < ph) __builtin_amdgcn_s_sleep(1);
  __syncthreads();
}

// ---------------- fp32 -> bf16 convert ----------------
__global__ __launch_bounds__(256) void k_cvt(const float* __restrict__ in,
                                             unsigned short* __restrict__ out, long n4) {
  long i = (long)blockIdx.x * 256 + threadIdx.x;
  long stride = (long)gridDim.x * 256;
  for (; i < n4; i += stride) {
    float4 v = reinterpret_cast<const float4*>(in)[i];
    ushort4 o;
    o.x = f2bf(v.x); o.y = f2bf(v.y); o.z = f2bf(v.z); o.w = f2bf(v.w);
    reinterpret_cast<ushort4*>(out)[i] = o;
  }
}

// ---------------- int64-vs-int32 caption detect ----------------
__global__ void k_detect_i64(const int* __restrict__ cap, int* __restrict__ flag) {
  __shared__ int s;
  if (threadIdx.x == 0) s = 0;
  __syncthreads();
  int acc = 0;
  for (int i = threadIdx.x; i < (B_ * L_) / 2; i += 256) acc |= cap[2 * i + 1];
  if (acc) atomicOr(&s, 1);
  __syncthreads();
  if (threadIdx.x == 0) flag[0] = (s == 0) ? 1 : 0;
}

// ---------------- embedding gather (rows r = l*64+b) ----------------
__global__ __launch_bounds__(256) void k_gather_emb(const float* __restrict__ emb,
                                                    const int* __restrict__ cap,
                                                    const int* __restrict__ flag,
                                                    unsigned short* __restrict__ aemb) {
  int r = blockIdx.x;
  int l = r >> 6, b = r & 63;
  int ci = b * L_ + l;
  int tok = flag[0] ? cap[2 * ci] : cap[ci];
  const float* src = emb + (size_t)tok * H_;
  unsigned short* dst = aemb + (size_t)r * H_;
  for (int c = threadIdx.x; c < H_; c += 256) dst[c] = f2bf(src[c]);
}

// ---------------- f16 weight pack kernels (one-time) ----------------
__global__ __launch_bounds__(256) void k_pack_enc(const float* __restrict__ whh,
                                                  uint4* __restrict__ wpe) {
  int idx = blockIdx.x * 256 + threadIdx.x;  // k2(256) x j(512)
  int k2 = idx >> 9, j = idx & 511;
  float2 r0 = *(const float2*)(whh + (size_t)(j) * 512 + 2 * k2);
  float2 r1 = *(const float2*)(whh + (size_t)(512 + j) * 512 + 2 * k2);
  float2 r2 = *(const float2*)(whh + (size_t)(1024 + j) * 512 + 2 * k2);
  float2 r3 = *(const float2*)(whh + (size_t)(1536 + j) * 512 + 2 * k2);
  wpe[idx] = make_uint4(f2h2(r0.x, r0.y), f2h2(r1.x, r1.y), f2h2(r2.x, r2.y), f2h2(r3.x, r3.y));
}

__global__ __launch_bounds__(256) void k_pack_dec(const float* __restrict__ dwih,
                                                  const float* __restrict__ dwhh,
                                                  uint4* __restrict__ wpd) {
  int idx = blockIdx.x * 256 + threadIdx.x;  // k2(512) x j(512)
  int k2 = idx >> 9, j = idx & 511;
  float2 r[4];
  if (k2 < 256) {
#pragma unroll
    for (int g = 0; g < 4; ++g)
      r[g] = *(const float2*)(dwih + (size_t)(g * 512 + j) * 1024 + 512 + 2 * k2);
  } else {
#pragma unroll
    for (int g = 0; g < 4; ++g)
      r[g] = *(const float2*)(dwhh + (size_t)(g * 512 + j) * 512 + 2 * (k2 - 256));
  }
  wpd[idx] = make_uint4(f2h2(r[0].x, r[0].y), f2h2(r[1].x, r[1].y),
                        f2h2(r[2].x, r[2].y), f2h2(r[3].x, r[3].y));
}

__global__ __launch_bounds__(256) void k_pack_attn2(const float* __restrict__ attnw,
                                                    uint4* __restrict__ wat2) {
  int idx = blockIdx.x * 256 + threadIdx.x;  // k8(64) x u(512)
  int k8 = idx >> 9, u = idx & 511;
  const float* p = attnw + (size_t)u * 1024 + 8 * k8;
  wat2[idx] = make_uint4(f2h2(p[0], p[1]), f2h2(p[2], p[3]),
                         f2h2(p[4], p[5]), f2h2(p[6], p[7]));
}

// ---------------- bf16 MFMA GEMM with register prefetch ----------------
// OUT_MODE 0: row-major; 1: FC row remap; 2: gate-packed [row][j][4]
template <int OUT_MODE>
__global__ __launch_bounds__(256) void k_gemm(const unsigned short* __restrict__ A, int lda,
                                              const unsigned short* __restrict__ Bm, int ldb,
                                              float* __restrict__ C, int N, int K,
                                              const float* __restrict__ bias0,
                                              const float* __restrict__ bias1) {
  __shared__ __align__(16) unsigned short As[128 * 40];
  __shared__ __align__(16) unsigned short Bs[128 * 40];
  const int tid = threadIdx.x;
  const int m0 = blockIdx.y * 128, n0 = blockIdx.x * 128;
  const int wave = tid >> 6, lane = tid & 63;
  const int wm = wave >> 1, wn = wave & 1;
  const int lr = lane & 15, lk = lane >> 4;

  f32x4 acc[4][4];
#pragma unroll
  for (int m = 0; m < 4; ++m)
#pragma unroll
    for (int n = 0; n < 4; ++n) acc[m][n] = (f32x4){0.f, 0.f, 0.f, 0.f};

  const int c0 = tid, c1 = tid + 256;
  const int ar0 = c0 >> 2, as0 = c0 & 3;
  const int ar1 = c1 >> 2, as1 = c1 & 3;
  const unsigned short* pa0 = A + (size_t)(m0 + ar0) * lda + as0 * 8;
  const unsigned short* pa1 = A + (size_t)(m0 + ar1) * lda + as1 * 8;
  const unsigned short* pb0 = Bm + (size_t)(n0 + ar0) * ldb + as0 * 8;
  const unsigned short* pb1 = Bm + (size_t)(n0 + ar1) * ldb + as1 * 8;

  uint4 va0 = *(const uint4*)(pa0);
  uint4 va1 = *(const uint4*)(pa1);
  uint4 vb0 = *(const uint4*)(pb0);
  uint4 vb1 = *(const uint4*)(pb1);

  for (int k0 = 0; k0 < K; k0 += 32) {
    *(uint4*)(As + ar0 * 40 + as0 * 8) = va0;
    *(uint4*)(As + ar1 * 40 + as1 * 8) = va1;
    *(uint4*)(Bs + ar0 * 40 + as0 * 8) = vb0;
    *(uint4*)(Bs + ar1 * 40 + as1 * 8) = vb1;
    __syncthreads();
    if (k0 + 32 < K) {
      va0 = *(const uint4*)(pa0 + k0 + 32);
      va1 = *(const uint4*)(pa1 + k0 + 32);
      vb0 = *(const uint4*)(pb0 + k0 + 32);
      vb1 = *(const uint4*)(pb1 + k0 + 32);
    }
    bf16x8 af[4], bfr[4];
#pragma unroll
    for (int m = 0; m < 4; ++m)
      af[m] = *(const bf16x8*)(As + (wm * 64 + m * 16 + lr) * 40 + lk * 8);
#pragma unroll
    for (int n = 0; n < 4; ++n)
      bfr[n] = *(const bf16x8*)(Bs + (wn * 64 + n * 16 + lr) * 40 + lk * 8);
#pragma unroll
    for (int m = 0; m < 4; ++m)
#pragma unroll
      for (int n = 0; n < 4; ++n)
        acc[m][n] = __builtin_amdgcn_mfma_f32_16x16x32_bf16(af[m], bfr[n], acc[m][n], 0, 0, 0);
    __syncthreads();
  }
#pragma unroll
  for (int m = 0; m < 4; ++m) {
#pragma unroll
    for (int n = 0; n < 4; ++n) {
      const int col = n0 + wn * 64 + n * 16 + lr;
      float bv = (bias0 ? bias0[col] : 0.f) + (bias1 ? bias1[col] : 0.f);
#pragma unroll
      for (int j = 0; j < 4; ++j) {
        const int row = m0 + wm * 64 + m * 16 + lk * 4 + j;
        float v = acc[m][n][j] + bv;
        if (OUT_MODE == 0) {
          C[(size_t)row * N + col] = v;
        } else if (OUT_MODE == 1) {
          int l = row >> 6, b = row & 63;
          C[((size_t)b * NDEC + l) * (size_t)N + col] = v;
        } else {
          C[((size_t)row * 512 + (col & 511)) * 4 + (col >> 9)] = v;
        }
      }
    }
  }
}

// ---------------- encoder: 8-block team, 2 b's (R13 verbatim) ----------------
__global__ __launch_bounds__(1024) void k_enc6(const float4* __restrict__ xg4,
                                               const uint4* __restrict__ wpe,
                                               float* __restrict__ encf,
                                               unsigned short* __restrict__ encbf,
                                               float* __restrict__ cfin,
                                               unsigned* __restrict__ h16E,  // [2][64][256]
                                               int* __restrict__ flagsE) {
  __shared__ __align__(16) unsigned short h16[2][512];
  __shared__ __align__(16) float psumG[2][16][4][64];  // 32 KB
  __shared__ __align__(16) float gsum[2][4][64];
  __shared__ unsigned short hnew[2][64];
  __shared__ __align__(16) uint4 wcache[112 * 64];     // 112 KB: k2<112, own j-slice
  const int bid = blockIdx.x, team = bid >> 3, m = bid & 7, tid = threadIdx.x;
  const int J0 = m * 64;
  int* tf = flagsE + team * 128;
  for (int i = tid; i < 112 * 64; i += 1024)
    wcache[i] = wpe[((i >> 6) << 9) | (J0 + (i & 63))];
  if (tid < 512) { h16[0][tid] = 0; h16[1][tid] = 0; }
  float c = 0.f;
  __syncthreads();
  const int j64 = tid & 63, ks = tid >> 6;   // 16 k-splits
  const int j = J0 + j64;
  const uint4* hp0 = (const uint4*)h16[0];
  const uint4* hp1 = (const uint4*)h16[1];
  for (int t = 0; t < T_; ++t) {
    float4 a0 = {0.f, 0.f, 0.f, 0.f}, a1 = a0;
    if (ks < 7) {
#pragma unroll
      for (int ii = 0; ii < 4; ++ii) {
        const int k8 = ks * 4 + ii;
        uint4 h0 = hp0[k8], h1 = hp1[k8];
        uint4 w0 = wcache[((k8 * 4 + 0) << 6) | j64];
        uint4 w1 = wcache[((k8 * 4 + 1) << 6) | j64];
        uint4 w2 = wcache[((k8 * 4 + 2) << 6) | j64];
        uint4 w3 = wcache[((k8 * 4 + 3) << 6) | j64];
        a0 = acc8(a0, h0, w0, w1, w2, w3);
        a1 = acc8(a1, h1, w0, w1, w2, w3);
      }
    } else {
#pragma unroll 2
      for (int ii = 0; ii < 4; ++ii) {
        const int k8 = ks * 4 + ii;
        uint4 h0 = hp0[k8], h1 = hp1[k8];
        uint4 w0 = wpe[((k8 * 4 + 0) << 9) | j];
        uint4 w1 = wpe[((k8 * 4 + 1) << 9) | j];
        uint4 w2 = wpe[((k8 * 4 + 2) << 9) | j];
        uint4 w3 = wpe[((k8 * 4 + 3) << 9) | j];
        a0 = acc8(a0, h0, w0, w1, w2, w3);
        a1 = acc8(a1, h1, w0, w1, w2, w3);
      }
    }
    psumG[0][ks][0][j64] = a0.x; psumG[0][ks][1][j64] = a0.y;
    psumG[0][ks][2][j64] = a0.z; psumG[0][ks][3][j64] = a0.w;
    psumG[1][ks][0][j64] = a1.x; psumG[1][ks][1][j64] = a1.y;
    psumG[1][ks][2][j64] = a1.z; psumG[1][ks][3][j64] = a1.w;
    __syncthreads();
    if (tid < 512) {
      const int b2 = tid >> 8, g = (tid >> 6) & 3, jj = tid & 63;
      float s = 0.f;
#pragma unroll
      for (int q = 0; q < 16; ++q) s += psumG[b2][q][g][jj];
      gsum[b2][g][jj] = s;
    }
    __syncthreads();
    if (tid < 128) {
      const int b2 = tid >> 6, jj = tid & 63;
      const int b = team * 2 + b2;
      float4 xa = xg4[((size_t)b * T_ + t) * 512 + J0 + jj];
      float g0 = xa.x + gsum[b2][0][jj];
      float g1 = xa.y + gsum[b2][1][jj];
      float g2 = xa.z + gsum[b2][2][jj];
      float g3 = xa.w + gsum[b2][3][jj];
      c = sigmoidf(g1) * c + sigmoidf(g0) * tanh_fast(g2);
      float h = sigmoidf(g3) * tanh_fast(c);
      size_t o = ((size_t)b * T_ + t) * 512 + J0 + jj;
      encf[o] = h;
      encbf[o] = f2bf(h);
      hnew[b2][jj] = f2h(h);
      if (t == T_ - 1) cfin[(size_t)b * 512 + J0 + jj] = c;
    }
    __syncthreads();
    const int p = t & 1;
    if (tid < 64) {
      const int b2 = tid >> 5, pp = tid & 31;
      const int b = team * 2 + b2;
      astu(h16E + (size_t)p * 64 * 256 + b * 256 + (J0 >> 1) + pp,
           f2h2(h2f(hnew[b2][2 * pp]), h2f(hnew[b2][2 * pp + 1])));
    }
    tsync8(tf, m, t + 1);
    if (t < T_ - 1) {
      if (tid < 512) {
        const int b2 = tid >> 8, pp = tid & 255;
        const int b = team * 2 + b2;
        ((unsigned*)h16[b2])[pp] = aldu(h16E + (size_t)p * 64 * 256 + b * 256 + pp);
      }
      __syncthreads();
    }
  }
}

// ---------------- decoder: 8-block team, 2 b's; 3 syncs/step; wat2 + wpdc LDS-cached ----------------
__global__ __launch_bounds__(1024) void k_dec8(const uint4* __restrict__ wpd,
                                               const uint4* __restrict__ wat2,
                                               const float* __restrict__ vw,
                                               const float4* __restrict__ eg4,
                                               const float* __restrict__ encpart,
                                               const unsigned short* __restrict__ encbf,
                                               const float* __restrict__ encf,
                                               const float* __restrict__ cfin,
                                               unsigned short* __restrict__ hsbf,
                                               float* __restrict__ scpart,   // [64][8][80]
                                               unsigned* __restrict__ ctxsl, // [64][256]
                                               unsigned* __restrict__ h16D,  // [2][64][256]
                                               int* __restrict__ flagsD) {
  __shared__ __align__(16) uint4 wat_c[64 * 64];          // 64 KB: wat2 j-slice
  __shared__ __align__(16) uint4 wpdc[32 * 64];           // 32 KB: wpd h-half rows 256..287
  __shared__ __align__(16) unsigned short xv16[2][1024];  // [b][ctx;h] f16
  __shared__ float vsmO[64];
  __shared__ float hwOwn[2][64];
  __shared__ float sc2[2][80], wts2[2][80];
  __shared__ __align__(16) float psumW[2][16][64];        // 8 KB
  __shared__ __align__(16) float psumG[2][16][4][64];     // 32 KB
  __shared__ __align__(16) float gsum[2][4][64];
  __shared__ __align__(16) float ctxp[2][8][64];
  __shared__ unsigned short hnew[2][64];
  const int bid = blockIdx.x, team = bid >> 3, m = bid & 7, tid = threadIdx.x;
  const int J0 = m * 64;
  int* tf = flagsD + team * 128;
  for (int i = tid; i < 64 * 64; i += 1024)
    wat_c[i] = wat2[((i >> 6) << 9) | (J0 + (i & 63))];
  for (int i = tid; i < 32 * 64; i += 1024)
    wpdc[i] = wpd[((256 + (i >> 6)) << 9) | (J0 + (i & 63))];
  {
    const int b2 = tid >> 9, jj = tid & 511;
    xv16[b2][512 + jj] = f2h(encf[((size_t)(team * 2 + b2) * T_ + T_ - 1) * 512 + jj]);
  }
  if (tid < 64) vsmO[tid] = vw[J0 + tid];
  float c = 0.f;
  if (tid < 128) c = cfin[(size_t)(team * 2 + (tid >> 6)) * 512 + J0 + (tid & 63)];
  __syncthreads();
  const int j64 = tid & 63, ks = tid >> 6;   // 16 k-splits
  const int j = J0 + j64;
  const uint4* xp0 = (const uint4*)xv16[0];
  const uint4* xp1 = (const uint4*)xv16[1];

  for (int l = 0; l < NDEC; ++l) {
    // ---- Phase A: gates h-half + hW, both b's, weight loaded once ----
    {
      float4 a0 = {0.f, 0.f, 0.f, 0.f}, a1 = a0;
      float s0 = 0.f, s1 = 0.f;
      if (ks < 2) {
#pragma unroll 2
        for (int ii = 0; ii < 4; ++ii) {
          const int ka = ks * 4 + ii;      // h-dim k8 in [0,8)
          const int kg = 64 + ka;
          uint4 hx0 = xp0[kg], hx1 = xp1[kg];
          uint4 w0 = wpdc[((ka * 4 + 0) << 6) | j64];
          uint4 w1 = wpdc[((ka * 4 + 1) << 6) | j64];
          uint4 w2 = wpdc[((ka * 4 + 2) << 6) | j64];
          uint4 w3 = wpdc[((ka * 4 + 3) << 6) | j64];
          a0 = acc8(a0, hx0, w0, w1, w2, w3);
          a1 = acc8(a1, hx1, w0, w1, w2, w3);
          uint4 wa = wat_c[(ka << 6) | j64];
          s0 = accS(s0, hx0, wa);
          s1 = accS(s1, hx1, wa);
        }
      } else {
#pragma unroll 2
        for (int ii = 0; ii < 4; ++ii) {
          const int ka = ks * 4 + ii;      // h-dim k8 in [8,64)
          const int kg = 64 + ka;
          uint4 hx0 = xp0[kg], hx1 = xp1[kg];
          uint4 w0 = wpd[((kg * 4 + 0) << 9) | j];
          uint4 w1 = wpd[((kg * 4 + 1) << 9) | j];
          uint4 w2 = wpd[((kg * 4 + 2) << 9) | j];
          uint4 w3 = wpd[((kg * 4 + 3) << 9) | j];
          a0 = acc8(a0, hx0, w0, w1, w2, w3);
          a1 = acc8(a1, hx1, w0, w1, w2, w3);
          uint4 wa = wat_c[(ka << 6) | j64];
          s0 = accS(s0, hx0, wa);
          s1 = accS(s1, hx1, wa);
        }
      }
      psumG[0][ks][0][j64] = a0.x; psumG[0][ks][1][j64] = a0.y;
      psumG[0][ks][2][j64] = a0.z; psumG[0][ks][3][j64] = a0.w;
      psumG[1][ks][0][j64] = a1.x; psumG[1][ks][1][j64] = a1.y;
      psumG[1][ks][2][j64] = a1.z; psumG[1][ks][3][j64] = a1.w;
      psumW[0][ks][j64] = s0;
      psumW[1][ks][j64] = s1;
    }
    __syncthreads();
    if (tid < 128) {
      const int b2 = tid >> 6, jj = tid & 63;
      float s = 0.f;
#pragma unroll
      for (int q = 0; q < 16; ++q) s += psumW[b2][q][jj];
      hwOwn[b2][jj] = s;
    }
    __syncthreads();
    // score partials over own u-slice, all 80 t, both b's
    {
      const int wv = tid >> 6, ln = tid & 63;
      const int b2 = wv & 1, b = team * 2 + b2;
      for (int t = wv >> 1; t < T_; t += 8) {
        float p = vsmO[ln] * tanh_fast(hwOwn[b2][ln] +
                  encpart[((size_t)b * T_ + t) * 512 + J0 + ln]);
#pragma unroll
        for (int s = 1; s < 64; s <<= 1) p += __shfl_xor(p, s, 64);
        if (ln == 0) astf(scpart + ((size_t)b * 8 + m) * 80 + t, p);
      }
    }
    tsync8(tf, m, 3 * l + 1);
    // ---- Phase B: sum partials -> softmax (both b) -> ctx j-slice ----
    if (tid < 160) {
      const int b2 = tid / 80, t = tid % 80;
      const int b = team * 2 + b2;
      float s = 0.f;
#pragma unroll
      for (int mm = 0; mm < 8; ++mm) s += aldf(scpart + ((size_t)b * 8 + mm) * 80 + t);
      sc2[b2][t] = s;
    }
    __syncthreads();
    if (tid < 128) {
      const int b2 = tid >> 6, ln = tid & 63;
      float x0 = sc2[b2][ln];
      float x1 = (ln < 16) ? sc2[b2][64 + ln] : -1e30f;
      float mx = fmaxf(x0, x1);
#pragma unroll
      for (int s = 1; s < 64; s <<= 1) mx = fmaxf(mx, __shfl_xor(mx, s, 64));
      float e0 = __expf(x0 - mx);
      float e1 = (ln < 16) ? __expf(x1 - mx) : 0.f;
      float sm = e0 + e1;
#pragma unroll
      for (int s = 1; s < 64; s <<= 1) sm += __shfl_xor(sm, s, 64);
      wts2[b2][ln] = e0 / sm;
      if (ln < 16) wts2[b2][64 + ln] = e1 / sm;
    }
    __syncthreads();
    // ctx final for own j-slice over all 80 t (10 KB/b read, L2-local)
    {
      const int b2 = tid >> 9, tq = (tid >> 6) & 7, jj = tid & 63;
      const int b = team * 2 + b2;
      float a = 0.f;
      for (int t = tq; t < T_; t += 8)
        a += wts2[b2][t] * bf2f(encbf[((size_t)b * T_ + t) * 512 + J0 + jj]);
      ctxp[b2][tq][jj] = a;
    }
    __syncthreads();
    if (tid < 64) {
      const int b2 = tid >> 5, pp = tid & 31;
      const int b = team * 2 + b2;
      float s0 = 0.f, s1 = 0.f;
#pragma unroll
      for (int q = 0; q < 8; ++q) {
        s0 += ctxp[b2][q][2 * pp];
        s1 += ctxp[b2][q][2 * pp + 1];
      }
      astu(ctxsl + (size_t)b * 256 + (J0 >> 1) + pp, f2h2(s0, s1));
    }
    tsync8(tf, m, 3 * l + 2);
    // ---- Phase C: read full ctx -> gates ctx-half -> LSTM -> h exchange ----
    if (tid < 512) {
      const int b2 = tid >> 8, pp = tid & 255;
      const int b = team * 2 + b2;
      ((unsigned*)xv16[b2])[pp] = aldu(ctxsl + (size_t)b * 256 + pp);
    }
    __syncthreads();
    {
      float4 a0 = {0.f, 0.f, 0.f, 0.f}, a1 = a0;
#pragma unroll 2
      for (int ii = 0; ii < 4; ++ii) {
        const int kc = ks * 4 + ii;        // ctx-dim k8 in [0,64)
        uint4 hx0 = xp0[kc], hx1 = xp1[kc];
        uint4 w0 = wpd[((kc * 4 + 0) << 9) | j];
        uint4 w1 = wpd[((kc * 4 + 1) << 9) | j];
        uint4 w2 = wpd[((kc * 4 + 2) << 9) | j];
        uint4 w3 = wpd[((kc * 4 + 3) << 9) | j];
        a0 = acc8(a0, hx0, w0, w1, w2, w3);
        a1 = acc8(a1, hx1, w0, w1, w2, w3);
      }
      psumG[0][ks][0][j64] += a0.x; psumG[0][ks][1][j64] += a0.y;
      psumG[0][ks][2][j64] += a0.z; psumG[0][ks][3][j64] += a0.w;
      psumG[1][ks][0][j64] += a1.x; psumG[1][ks][1][j64] += a1.y;
      psumG[1][ks][2][j64] += a1.z; psumG[1][ks][3][j64] += a1.w;
    }
    __syncthreads();
    if (tid < 512) {
      const int b2 = tid >> 8, g = (tid >> 6) & 3, jj = tid & 63;
      float s = 0.f;
#pragma unroll
      for (int q = 0; q < 16; ++q) s += psumG[b2][q][g][jj];
      gsum[b2][g][jj] = s;
    }
    __syncthreads();
    if (tid < 128) {
      const int b2 = tid >> 6, jj = tid & 63;
      const int b = team * 2 + b2;
      float4 xa = eg4[((size_t)l * 64 + b) * 512 + J0 + jj];
      float g0 = xa.x + gsum[b2][0][jj];
      float g1 = xa.y + gsum[b2][1][jj];
      float g2 = xa.z + gsum[b2][2][jj];
      float g3 = xa.w + gsum[b2][3][jj];
      c = sigmoidf(g1) * c + sigmoidf(g0) * tanh_fast(g2);
      float h = sigmoidf(g3) * tanh_fast(c);
      hsbf[((size_t)l * 64 + b) * 512 + J0 + jj] = f2bf(h);
      hnew[b2][jj] = f2h(h);
    }
    __syncthreads();
    const int p = l & 1;
    if (tid < 64) {
      const int b2 = tid >> 5, pp = tid & 31;
      const int b = team * 2 + b2;
      astu(h16D + (size_t)p * 64 * 256 + b * 256 + (J0 >> 1) + pp,
           f2h2(h2f(hnew[b2][2 * pp]), h2f(hnew[b2][2 * pp + 1])));
    }
    tsync8(tf, m, 3 * l + 3);
    if (l < NDEC - 1) {
      if (tid < 512) {
        const int b2 = tid >> 8, pp = tid & 255;
        const int b = team * 2 + b2;
        ((unsigned*)(&xv16[b2][512]))[pp] = aldu(h16D + (size_t)p * 64 * 256 + b * 256 + pp);
      }
      __syncthreads();
    }
  }
}

// ---------------- launch ----------------
extern "C" void kernel_launch(void* const* d_in, const int* in_sizes, int n_in,
                              void* d_out, int out_size, void* d_ws, size_t ws_size,
                              hipStream_t stream) {
  const float* video = (const float*)d_in[0];
  const int* captions = (const int*)d_in[1];
  const float* emb = (const float*)d_in[2];
  const float* eWih = (const float*)d_in[3];
  const float* eWhh = (const float*)d_in[4];
  const float* ebih = (const float*)d_in[5];
  const float* ebhh = (const float*)d_in[6];
  const float* attnW = (const float*)d_in[7];
  const float* attnb = (const float*)d_in[8];
  const float* vw = (const float*)d_in[9];
  const float* dWih = (const float*)d_in[10];
  const float* dWhh = (const float*)d_in[11];
  const float* dbih = (const float*)d_in[12];
  const float* dbhh = (const float*)d_in[13];
  const float* fcW = (const float*)d_in[14];
  const float* fcb = (const float*)d_in[15];

  char* ws = (char*)d_ws;
  unsigned short* vid_bf = (unsigned short*)(ws + 0);            // dead after K1
  unsigned short* fcw_bf = (unsigned short*)(ws + 0);            // [0, 32,768,000) after K1
  const size_t G = 32768000ull;  // team-exchange gap (post-K1 only)
  unsigned* h16E = (unsigned*)(ws + G + 0);            // 131,072
  unsigned* h16D = (unsigned*)(ws + G + 131072);       // 131,072
  float* scpartD = (float*)(ws + G + 262144);          // 163,840 ([64][8][80] f32)
  unsigned* ctxslD = (unsigned*)(ws + G + 425984);     // 65,536 ([64][256] u32)
  int* flagsE = (int*)(ws + G + 491520);               // 16,384
  int* flagsD = (int*)(ws + G + 507904);               // 16,384 (ends 524,288 < 786,432)
  unsigned short* hs_bf = (unsigned short*)(ws + 33554432ull);
  uint4* wpd = (uint4*)(ws + 35520512ull);                       // after K1
  uint4* wpe = (uint4*)(ws + 39714816ull);                       // after K1
  float* xg4 = (float*)(ws + 41943040ull);                       // dead after enc
  float* encpart = (float*)(ws + 41943040ull);                   // after enc
  float* eg4 = (float*)(ws + 52428800ull);                       // after enc
  unsigned short* aemb = (unsigned short*)(ws + 68157440ull);    // after enc
  unsigned short* ewih_bf = (unsigned short*)(ws + 83886080ull);
  float* encf = (float*)(ws + 100663296ull);
  unsigned short* encbf = (unsigned short*)(ws + 111149056ull);
  unsigned short* attnw_bf = (unsigned short*)(ws + 116391936ull);
  unsigned short* dwih_bf = (unsigned short*)(ws + 117440512ull);
  uint4* wat2 = (uint4*)(ws + 121634816ull);
  float* cfin = (float*)(ws + 122159104ull);
  int* flag = (int*)(ws + 122290176ull);

  auto cvt = [&](const float* in, unsigned short* out, long n) {
    long n4 = n / 4;
    int blocks = (int)((n4 + 255) / 256);
    if (blocks > 2048) blocks = 2048;
    k_cvt<<<blocks, 256, 0, stream>>>(in, out, n4);
  };
  cvt(video, vid_bf, 5120L * 4096);
  cvt(eWih, ewih_bf, 2048L * 4096);
  cvt(attnW, attnw_bf, 512L * 1024);
  cvt(dWih, dwih_bf, 2048L * 1024);
  k_detect_i64<<<1, 256, 0, stream>>>(captions, flag);

  // K1: X_gates = video @ enc_Wih^T + ebih + ebhh  -> gate-packed [r][j][4]
  k_gemm<2><<<dim3(16, 40), 256, 0, stream>>>(vid_bf, 4096, ewih_bf, 4096, xg4, 2048, 4096, ebih, ebhh);
  cvt(fcW, fcw_bf, 32000L * 512);

  // f16 weight packs (overlap vid_bf's old region -> must follow K1)
  k_pack_enc<<<512, 256, 0, stream>>>(eWhh, wpe);
  k_pack_dec<<<1024, 256, 0, stream>>>(dWih, dWhh, wpd);
  k_pack_attn2<<<128, 256, 0, stream>>>(attnW, wat2);

  // zero team-sync flags (gap region clobbered by cvt(video) -> zero AFTER K1)
  hipMemsetAsync(ws + G + 491520, 0, 32768, stream);

  k_enc6<<<256, 1024, 0, stream>>>((const float4*)xg4, wpe, encf, encbf, cfin, h16E, flagsE);

  k_gather_emb<<<1920, 256, 0, stream>>>(emb, captions, flag, aemb);
  // EncPart = enc_out @ attn_W[:,512:]^T + attn_b   [5120 x 512]
  k_gemm<0><<<dim3(4, 40), 256, 0, stream>>>(encbf, 512, attnw_bf + 512, 1024, encpart, 512, 512, attnb, nullptr);
  // E_gates = emb[tok] @ dec_Wih[:,:512]^T + dbih + dbhh -> gate-packed
  k_gemm<2><<<dim3(16, 15), 256, 0, stream>>>(aemb, 512, dwih_bf, 1024, eg4, 2048, 512, dbih, dbhh);

  k_dec8<<<256, 1024, 0, stream>>>(wpd, wat2, vw, (const float4*)eg4, encpart, encbf, encf,
                                   cfin, hs_bf, scpartD, ctxslD, h16D, flagsD);

  // FC: out[b][l][v] = Hs @ fc_W^T + fc_b   [1920 x 32000]
  k_gemm<1><<<dim3(250, 15), 256, 0, stream>>>(hs_bf, 512, fcw_bf, 512, (float*)d_out, 32000, 512, fcb, nullptr);
}